// Round 15
// baseline (166.963 us; speedup 1.0000x reference)
//
#include <hip/hip_runtime.h>
#include <hip/hip_bf16.h>
#include <math.h>
#include <stdint.h>

#define B_DIM 2
#define S_DIM 2048
#define E_DIM 768
#define H_DIM 8
#define D_DIM 96
#define M_DIM (B_DIM*S_DIM)          // 4096
#define SCALE_F 0.10206207261596575f // 96^-0.5

typedef _Float16 f16x8 __attribute__((ext_vector_type(8)));
typedef float    f32x4  __attribute__((ext_vector_type(4)));
typedef float    f32x16 __attribute__((ext_vector_type(16)));

#define MFMA16H(a,b,c) __builtin_amdgcn_mfma_f32_16x16x32_f16(a,b,c,0,0,0)
#define MFMA32H(a,b,c) __builtin_amdgcn_mfma_f32_32x32x16_f16(a,b,c,0,0,0)

__device__ inline unsigned short f2h(float f) {
    return __builtin_bit_cast(unsigned short, (_Float16)f);
}
__device__ inline unsigned int pk2(float a, float b) {   // v_cvt_pkrtz_f16_f32
    return __builtin_bit_cast(unsigned int, __builtin_amdgcn_cvt_pkrtz(a, b));
}
__device__ inline uint4 cvt8(float4 x, float4 y) {
    uint4 r;
    r.x = pk2(x.x, x.y); r.y = pk2(x.z, x.w);
    r.z = pk2(y.x, y.y); r.w = pk2(y.z, y.w);
    return r;
}

// CK-style async global->LDS, 16B per lane.
__device__ inline void gload16(const void* g, void* l) {
    auto gp = reinterpret_cast<const __attribute__((address_space(1))) uint32_t*>(
        reinterpret_cast<uintptr_t>(g));
    auto lp = reinterpret_cast<__attribute__((address_space(3))) uint32_t*>(
        reinterpret_cast<uintptr_t>(l));
    __builtin_amdgcn_global_load_lds(gp, lp, 16, 0, 0);
}

// ---------------------------------------------------------------------------
// Weight prep only (x-convert now fused into gemm_qk):
//   W{q,k,o} fp32 [k][n] -> W^T fp16 [n][k], 64x64 tiles. 432 blocks.
// ---------------------------------------------------------------------------
__global__ __launch_bounds__(256) void prep_kernel(
    const float* __restrict__ W0, const float* __restrict__ W1,
    const float* __restrict__ W2,
    unsigned short* __restrict__ T0, unsigned short* __restrict__ T1,
    unsigned short* __restrict__ T2)
{
    const int tid = threadIdx.x;
    int idx = blockIdx.x;               // 0..431
    int z = idx / 144, rem = idx % 144;
    const float* W; unsigned short* T;
    if (z == 0)      { W = W0; T = T0; }
    else if (z == 1) { W = W1; T = T1; }
    else             { W = W2; T = T2; }
    int k0 = (rem / 12) << 6, n0 = (rem % 12) << 6;

    __shared__ float tile[64][65];
    const int r = tid >> 4, c4 = (tid & 15) << 2;
    #pragma unroll
    for (int i = 0; i < 4; ++i) {
        float4 v = *(const float4*)(W + (size_t)(k0 + r + i*16)*E_DIM + n0 + c4);
        tile[r + i*16][c4+0] = v.x; tile[r + i*16][c4+1] = v.y;
        tile[r + i*16][c4+2] = v.z; tile[r + i*16][c4+3] = v.w;
    }
    __syncthreads();
    #pragma unroll
    for (int i = 0; i < 4; ++i) {
        int n = r + i*16;
        ushort4 h;
        h.x = f2h(tile[c4+0][n]); h.y = f2h(tile[c4+1][n]);
        h.z = f2h(tile[c4+2][n]); h.w = f2h(tile[c4+3][n]);
        *(ushort4*)(T + (size_t)(n0 + n)*E_DIM + k0 + c4) = h;
    }
}

// ---------------------------------------------------------------------------
// Fused Q/K projection, fp32 x read DIRECTLY (in-register convert during
// A-staging, register-prefetched across the barrier). 128x64 tile, BK=64 as
// two 32-k panels, grid (24,32) = 768 blocks = 3/CU. B^T via gload16.
// ---------------------------------------------------------------------------
__global__ __launch_bounds__(256) void gemm_qk_kernel(
    const float* __restrict__ X, const unsigned short* __restrict__ Bt,
    const float* __restrict__ bq, const float* __restrict__ bk,
    unsigned short* __restrict__ Qf, unsigned short* __restrict__ Kf)
{
    __shared__ unsigned short sA[2*128*32];   // [panel][m][k32]
    __shared__ unsigned short sB[2*64*32];    // [panel][n][k32]

    const int tid  = threadIdx.x;
    const int lane = tid & 63;
    const int w    = tid >> 6;
    const int qn   = lane & 15, quad = lane >> 4;
    const int wm   = w & 1, wn = w >> 1;
    const int row0 = blockIdx.y << 7;
    const int col0 = blockIdx.x << 6;   // 64-tiles: Q (<768) / K (>=768) never straddle

    const int ar = tid >> 2;            // 0..63
    const int ak = (tid & 3) << 3;      // 0,8,16,24

    const float* gA0 = X + (size_t)(row0 + ar)*E_DIM + ak;        // rows 0-63
    const float* gA1 = X + (size_t)(row0 + ar + 64)*E_DIM + ak;   // rows 64-127
    const unsigned short* gB = Bt + (size_t)(col0 + ar)*E_DIM + ak;

    f32x4 acc[4][2];
    #pragma unroll
    for (int mt = 0; mt < 4; ++mt)
        #pragma unroll
        for (int nt = 0; nt < 2; ++nt)
            { acc[mt][nt][0]=0.f; acc[mt][nt][1]=0.f; acc[mt][nt][2]=0.f; acc[mt][nt][3]=0.f; }

    float4 pa[8];
    {
        pa[0] = *(const float4*)(gA0);      pa[1] = *(const float4*)(gA0 + 4);
        pa[2] = *(const float4*)(gA1);      pa[3] = *(const float4*)(gA1 + 4);
        pa[4] = *(const float4*)(gA0 + 32); pa[5] = *(const float4*)(gA0 + 36);
        pa[6] = *(const float4*)(gA1 + 32); pa[7] = *(const float4*)(gA1 + 36);
    }

    for (int k0 = 0; k0 < E_DIM; k0 += 64) {
        __syncthreads();
        *(uint4*)&sA[       ar*32 + ak] = cvt8(pa[0], pa[1]);   // panel0, rows 0-63
        *(uint4*)&sA[2048 + ar*32 + ak] = cvt8(pa[2], pa[3]);   // panel0, rows 64-127
        *(uint4*)&sA[4096 + ar*32 + ak] = cvt8(pa[4], pa[5]);   // panel1, rows 0-63
        *(uint4*)&sA[6144 + ar*32 + ak] = cvt8(pa[6], pa[7]);   // panel1, rows 64-127
        gload16(gB + k0,      sB + tid*8);
        gload16(gB + k0 + 32, sB + 2048 + tid*8);
        __syncthreads();

        if (k0 + 64 < E_DIM) {
            int kn = k0 + 64;
            pa[0] = *(const float4*)(gA0 + kn);      pa[1] = *(const float4*)(gA0 + kn + 4);
            pa[2] = *(const float4*)(gA1 + kn);      pa[3] = *(const float4*)(gA1 + kn + 4);
            pa[4] = *(const float4*)(gA0 + kn + 32); pa[5] = *(const float4*)(gA0 + kn + 36);
            pa[6] = *(const float4*)(gA1 + kn + 32); pa[7] = *(const float4*)(gA1 + kn + 36);
        }

        #pragma unroll
        for (int kk = 0; kk < 2; ++kk) {
            f16x8 af[4], bf[2];
            #pragma unroll
            for (int mt = 0; mt < 4; ++mt)
                af[mt] = *(const f16x8*)&sA[kk*4096 + (wm*64 + mt*16 + qn)*32 + quad*8];
            #pragma unroll
            for (int nt = 0; nt < 2; ++nt)
                bf[nt] = *(const f16x8*)&sB[kk*2048 + (wn*32 + nt*16 + qn)*32 + quad*8];
            #pragma unroll
            for (int mt = 0; mt < 4; ++mt)
                #pragma unroll
                for (int nt = 0; nt < 2; ++nt)
                    acc[mt][nt] = MFMA16H(af[mt], bf[nt], acc[mt][nt]);
        }
    }

    #pragma unroll
    for (int nt = 0; nt < 2; ++nt) {
        int n = col0 + wn*32 + nt*16 + qn;
        bool isQ = n < E_DIM;
        float bias = isQ ? bq[n] : bk[n - E_DIM];
        unsigned short* op = isQ ? Qf : Kf;
        int nc = isQ ? n : n - E_DIM;
        #pragma unroll
        for (int mt = 0; mt < 4; ++mt)
            #pragma unroll
            for (int r = 0; r < 4; ++r) {
                int m = row0 + wm*64 + mt*16 + quad*4 + r;
                op[(size_t)m*E_DIM + nc] = f2h(acc[mt][nt][r] + bias);
            }
    }
}

// ---------------------------------------------------------------------------
// Flash attention (R13 config, unchanged — 50.3 µs plateau): 32x32x16,
// 4 waves, q-tile 128, key-split x2, dbuf sKh/sKt (one barrier/iter),
// strides 104/72/72, swapped PV, __expf.
// ---------------------------------------------------------------------------
__global__ __launch_bounds__(256) void attn_mfma_kernel(
    const unsigned short* __restrict__ Qf, const unsigned short* __restrict__ Kf,
    unsigned short* __restrict__ O0, unsigned short* __restrict__ O1,
    float2* __restrict__ ml)
{
    __shared__ unsigned short sKh[2][64][104];  // [buf][key][d]
    __shared__ unsigned short sKt[2][96][72];   // [buf][e][key]
    __shared__ unsigned short sPs[128][72];     // [q][key]

    const int tid  = threadIdx.x;
    const int w    = tid >> 6;       // wave 0..3: q rows [w*32, w*32+32)
    const int lane = tid & 63;
    const int col  = lane & 31;      // q for state/S^T-n/PV-n; e for PV-A rows
    const int half = lane >> 5;      // k-half selector
    const int b    = blockIdx.z >> 1;
    const int kh   = blockIdx.z & 1; // key half
    const int h    = blockIdx.y;
    const int q0   = blockIdx.x << 7;
    const int key0 = kh << 10;       // 0 or 1024

    // Q B-frags: B[k=d][n=q], lane reads 8 contiguous d at row q=col
    f16x8 qf[6];
    {
        const size_t ro = ((size_t)(b*S_DIM + q0 + w*32 + col))*E_DIM
                          + h*D_DIM + half*8;
        #pragma unroll
        for (int kc = 0; kc < 6; ++kc)
            qf[kc] = *(const f16x8*)(Qf + ro + kc*16);
    }

    f32x16 o[3];
    #pragma unroll
    for (int nt = 0; nt < 3; ++nt)
        #pragma unroll
        for (int r = 0; r < 16; ++r) o[nt][r] = 0.f;
    float m_i = -INFINITY, l_i = 0.f;

    // staging (threads 0-127): rows {2sp, 2sp+1}, d range [dq*24, dq*24+24)
    const bool stager = tid < 128;
    const int st = tid & 127;
    const int sp = st >> 2;          // 0..31
    const int dq = st & 3;           // 0..3

    uint4 r0[3], r1[3];
    if (stager) {
        const size_t g0 = ((size_t)(b*S_DIM + key0 + 2*sp))*E_DIM + h*D_DIM + dq*24;
        #pragma unroll
        for (int i = 0; i < 3; ++i) {
            r0[i] = *(const uint4*)(Kf + g0 + 8*i);
            r1[i] = *(const uint4*)(Kf + g0 + E_DIM + 8*i);
        }
    }

    for (int kt = 0; kt < 16; ++kt) {
        const int p = kt & 1;
        if (stager) {
            #pragma unroll
            for (int i = 0; i < 3; ++i) {
                *(uint4*)&sKh[p][2*sp  ][dq*24 + 8*i] = r0[i];
                *(uint4*)&sKh[p][2*sp+1][dq*24 + 8*i] = r1[i];
            }
            const unsigned short* p0 = (const unsigned short*)r0;
            const unsigned short* p1 = (const unsigned short*)r1;
            #pragma unroll
            for (int c = 0; c < 24; ++c) {
                unsigned int pk = (unsigned int)p0[c] | ((unsigned int)p1[c] << 16);
                *(unsigned int*)&sKt[p][dq*24 + c][2*sp] = pk;
            }
        }
        __syncthreads();   // buf[p] visible; also fences buf[p] reads of kt-2

        // prefetch next tile (overlaps with compute below)
        if (stager && kt + 1 < 16) {
            const size_t g0 = ((size_t)(b*S_DIM + key0 + (kt+1)*64 + 2*sp))*E_DIM
                              + h*D_DIM + dq*24;
            #pragma unroll
            for (int i = 0; i < 3; ++i) {
                r0[i] = *(const uint4*)(Kf + g0 + 8*i);
                r1[i] = *(const uint4*)(Kf + g0 + E_DIM + 8*i);
            }
        }

        // ---- S^T = K·Q^T (fp16), D[m=key][n=q] ----
        f32x16 s[2];
        #pragma unroll
        for (int mt = 0; mt < 2; ++mt) {
            f32x16 acc;
            #pragma unroll
            for (int r = 0; r < 16; ++r) acc[r] = 0.f;
            #pragma unroll
            for (int kc = 0; kc < 6; ++kc) {
                f16x8 ah = *(const f16x8*)&sKh[p][mt*32 + col][kc*16 + half*8];
                acc = MFMA32H(ah, qf[kc], acc);
            }
            s[mt] = acc;
        }

        // ---- online softmax, per-lane state (q = col) ----
        float mx = s[0][0];
        #pragma unroll
        for (int mt = 0; mt < 2; ++mt)
            #pragma unroll
            for (int r = 0; r < 16; ++r) mx = fmaxf(mx, s[mt][r]);
        mx = fmaxf(mx, __shfl_xor(mx, 32));

        float m_new = fmaxf(m_i, mx);
        float alpha = __expf(m_i - m_new);
        m_i = m_new;

        float psum = 0.f;
        #pragma unroll
        for (int mt = 0; mt < 2; ++mt)
            #pragma unroll
            for (int g = 0; g < 4; ++g) {
                float e0 = __expf(s[mt][4*g+0] - m_new);
                float e1 = __expf(s[mt][4*g+1] - m_new);
                float e2 = __expf(s[mt][4*g+2] - m_new);
                float e3 = __expf(s[mt][4*g+3] - m_new);
                psum += e0 + e1 + e2 + e3;
                ushort4 pk;
                pk.x = f2h(e0); pk.y = f2h(e1); pk.z = f2h(e2); pk.w = f2h(e3);
                *(ushort4*)&sPs[w*32 + col][mt*32 + 8*g + 4*half] = pk;
            }
        psum += __shfl_xor(psum, 32);
        l_i = l_i * alpha + psum;

        // rescale O: accumulator n-dim = q = col -> lane's own alpha
        #pragma unroll
        for (int nt = 0; nt < 3; ++nt)
            #pragma unroll
            for (int r = 0; r < 16; ++r) o[nt][r] *= alpha;

        // ---- PV swapped: O^T[e][q] += V^T·P^T (A = sKt rows, B = sPs rows) ----
        #pragma unroll
        for (int kc = 0; kc < 4; ++kc) {
            f16x8 pb = *(const f16x8*)&sPs[w*32 + col][kc*16 + half*8];
            #pragma unroll
            for (int nt = 0; nt < 3; ++nt) {
                f16x8 va = *(const f16x8*)&sKt[p][nt*32 + col][kc*16 + half*8];
                o[nt] = MFMA32H(va, pb, o[nt]);
            }
        }
    }

    // ---- epilogue: unnormalized Ohat (fp16), lane owns row q = col ----
    unsigned short* Ob = (kh ? O1 : O0)
        + ((size_t)(b*S_DIM + q0 + w*32 + col))*E_DIM + h*D_DIM;
    #pragma unroll
    for (int nt = 0; nt < 3; ++nt)
        #pragma unroll
        for (int rg = 0; rg < 4; ++rg) {
            ushort4 pk;
            pk.x = f2h(o[nt][4*rg+0]); pk.y = f2h(o[nt][4*rg+1]);
            pk.z = f2h(o[nt][4*rg+2]); pk.w = f2h(o[nt][4*rg+3]);
            *(ushort4*)(Ob + nt*32 + 8*rg + 4*half) = pk;
        }
    if (lane < 32) {
        int q = q0 + w*32 + lane;
        ml[((size_t)(kh*B_DIM + b)*H_DIM + h)*S_DIM + q] = make_float2(m_i, l_i);
    }
}

// ---------------------------------------------------------------------------
// Merge scales from (m,l), computed inline: s_i = exp(m_i - m) * SCALE / l
// ---------------------------------------------------------------------------
__device__ inline float2 mkscale(const float2* __restrict__ ml, int m, int h) {
    int b = m >> 11, q = m & (S_DIM - 1);
    float2 e0 = ml[((size_t)b*H_DIM + h)*S_DIM + q];
    float2 e1 = ml[((size_t)(B_DIM + b)*H_DIM + h)*S_DIM + q];
    float mm = fmaxf(e0.x, e1.x);
    float w0 = __expf(e0.x - mm), w1 = __expf(e1.x - mm);
    float inv = SCALE_F / (e0.y*w0 + e1.y*w1);
    return make_float2(w0*inv, w1*inv);
}

// ---------------------------------------------------------------------------
// Output projection + fused partial-combine (R13 config): 64x64 tile,
// grid (12,64) = 768 blocks = 3/CU. ctx = O0*s0 + O1*s1 (packed fp16) in
// A-staging; scales recomputed at head boundaries. out = ctx·Wo^T + bo.
// ---------------------------------------------------------------------------
__global__ __launch_bounds__(256) void gemm_out_kernel(
    const unsigned short* __restrict__ O0, const unsigned short* __restrict__ O1,
    const float2* __restrict__ ml, const unsigned short* __restrict__ Bt,
    const float* __restrict__ bo, float* __restrict__ out)
{
    __shared__ unsigned short sA[64*32];
    __shared__ unsigned short sB[64*32];

    const int tid  = threadIdx.x;
    const int lane = tid & 63;
    const int w    = tid >> 6;
    const int qn   = lane & 15, quad = lane >> 4;
    const int wm   = w & 1, wn = w >> 1;
    const int row0 = blockIdx.y << 6;
    const int col0 = blockIdx.x << 6;

    const int ar = tid >> 2;            // 0..63
    const int ak = (tid & 3) << 3;      // 0,8,16,24

    const size_t r0o = (size_t)(row0 + ar)*E_DIM;
    const unsigned short* gB = Bt + (size_t)(col0 + ar)*E_DIM + ak;

    f32x4 acc[2][2];
    #pragma unroll
    for (int mt = 0; mt < 2; ++mt)
        #pragma unroll
        for (int nt = 0; nt < 2; ++nt)
            { acc[mt][nt][0]=0.f; acc[mt][nt][1]=0.f; acc[mt][nt][2]=0.f; acc[mt][nt][3]=0.f; }

    f16x8 u0 = *(const f16x8*)(O0 + r0o + ak);
    f16x8 v0 = *(const f16x8*)(O1 + r0o + ak);
    float2 s0 = mkscale(ml, row0 + ar, 0);
    _Float16 hx = (_Float16)s0.x, hy = (_Float16)s0.y;

    for (int k0 = 0; k0 < E_DIM; k0 += 32) {
        __syncthreads();
        {
            f16x8 c0 = u0 * hx + v0 * hy;
            *(f16x8*)&sA[ar*32 + ak] = c0;
        }
        gload16(gB + k0, sB + tid*8);
        __syncthreads();

        if (k0 + 32 < E_DIM) {
            int kn = k0 + 32;
            u0 = *(const f16x8*)(O0 + r0o + kn + ak);
            v0 = *(const f16x8*)(O1 + r0o + kn + ak);
            if ((kn % D_DIM) == 0) {    // head boundary (every 3rd chunk)
                s0 = mkscale(ml, row0 + ar, kn / D_DIM);
                hx = (_Float16)s0.x; hy = (_Float16)s0.y;
            }
        }

        f16x8 af[2], bf[2];
        #pragma unroll
        for (int mt = 0; mt < 2; ++mt)
            af[mt] = *(const f16x8*)&sA[(wm*32 + mt*16 + qn)*32 + quad*8];
        #pragma unroll
        for (int nt = 0; nt < 2; ++nt)
            bf[nt] = *(const f16x8*)&sB[(wn*32 + nt*16 + qn)*32 + quad*8];
        #pragma unroll
        for (int mt = 0; mt < 2; ++mt)
            #pragma unroll
            for (int nt = 0; nt < 2; ++nt)
                acc[mt][nt] = MFMA16H(af[mt], bf[nt], acc[mt][nt]);
    }

    #pragma unroll
    for (int nt = 0; nt < 2; ++nt) {
        int n = col0 + wn*32 + nt*16 + qn;
        float bias = bo[n];
        #pragma unroll
        for (int mt = 0; mt < 2; ++mt)
            #pragma unroll
            for (int r = 0; r < 4; ++r) {
                int m = row0 + wm*32 + mt*16 + quad*4 + r;
                out[(size_t)m*E_DIM + n] = acc[mt][nt][r] + bias;
            }
    }
}

// ---------------------------------------------------------------------------
extern "C" void kernel_launch(void* const* d_in, const int* in_sizes, int n_in,
                              void* d_out, int out_size, void* d_ws, size_t ws_size,
                              hipStream_t stream)
{
    const float* x  = (const float*)d_in[0];
    const float* Wq = (const float*)d_in[1];
    const float* bq = (const float*)d_in[2];
    const float* Wk = (const float*)d_in[3];
    const float* bk = (const float*)d_in[4];
    const float* Wo = (const float*)d_in[5];
    const float* bo = (const float*)d_in[6];
    float* out = (float*)d_out;

    const size_t NE = (size_t)M_DIM * E_DIM;        // 3.1M elems
    const size_t WE = (size_t)E_DIM * E_DIM;        // 590K elems
    unsigned short* WqkT  = (unsigned short*)d_ws;  // 2*WE  [Wq^T | Wk^T] fp16
    unsigned short* WoT   = WqkT + 2*WE;            // WE
    unsigned short* Qf    = WoT + WE;               // NE
    unsigned short* Kf    = Qf + NE;                // NE
    unsigned short* Oh0   = Kf + NE;                // NE
    unsigned short* Oh1   = Oh0 + NE;               // NE
    float2*         mlbuf = (float2*)(Oh1 + NE);    // 2*B*H*S float2 = 512 KB

    dim3 blk(256);
    hipLaunchKernelGGL(prep_kernel, dim3(432), blk, 0, stream,
                       Wq, Wk, Wo, WqkT, WqkT + WE, WoT);

    hipLaunchKernelGGL(gemm_qk_kernel, dim3(24,32), blk, 0, stream,
                       x, WqkT, bq, bk, Qf, Kf);

    hipLaunchKernelGGL(attn_mfma_kernel, dim3(S_DIM/128, H_DIM, B_DIM*2), blk, 0,
                       stream, Qf, Kf, Oh0, Oh1, mlbuf);

    hipLaunchKernelGGL(gemm_out_kernel, dim3(12,64), blk, 0, stream,
                       Oh0, Oh1, mlbuf, WoT, bo, out);
}

// Round 16
// 163.140 us; speedup vs baseline: 1.0234x; 1.0234x over previous
//
#include <hip/hip_runtime.h>
#include <hip/hip_bf16.h>
#include <math.h>
#include <stdint.h>

#define B_DIM 2
#define S_DIM 2048
#define E_DIM 768
#define H_DIM 8
#define D_DIM 96
#define M_DIM (B_DIM*S_DIM)          // 4096
#define SCALE_F 0.10206207261596575f // 96^-0.5

typedef _Float16 f16x8 __attribute__((ext_vector_type(8)));
typedef float    f32x4  __attribute__((ext_vector_type(4)));
typedef float    f32x16 __attribute__((ext_vector_type(16)));

#define MFMA16H(a,b,c) __builtin_amdgcn_mfma_f32_16x16x32_f16(a,b,c,0,0,0)
#define MFMA32H(a,b,c) __builtin_amdgcn_mfma_f32_32x32x16_f16(a,b,c,0,0,0)

__device__ inline unsigned short f2h(float f) {
    return __builtin_bit_cast(unsigned short, (_Float16)f);
}

// CK-style async global->LDS, 16B per lane.
__device__ inline void gload16(const void* g, void* l) {
    auto gp = reinterpret_cast<const __attribute__((address_space(1))) uint32_t*>(
        reinterpret_cast<uintptr_t>(g));
    auto lp = reinterpret_cast<__attribute__((address_space(3))) uint32_t*>(
        reinterpret_cast<uintptr_t>(l));
    __builtin_amdgcn_global_load_lds(gp, lp, 16, 0, 0);
}

// ---------------------------------------------------------------------------
// Fused preprocessing, ONE launch (R13-proven; streaming x-convert overlaps
// internally — fusing it into gemm_qk staging regressed, R14):
//   blocks [0, 3072):   x [4096,768] fp32 -> fp16
//   blocks [3072, 3504): W{q,k,o} fp32 [k][n] -> W^T fp16 [n][k], 64x64 tiles
// ---------------------------------------------------------------------------
__global__ __launch_bounds__(256) void prep_kernel(
    const float* __restrict__ X,
    const float* __restrict__ W0, const float* __restrict__ W1,
    const float* __restrict__ W2,
    unsigned short* __restrict__ Xf,
    unsigned short* __restrict__ T0, unsigned short* __restrict__ T1,
    unsigned short* __restrict__ T2)
{
    const int tid = threadIdx.x;
    if (blockIdx.x < 3072) {
        int i = (blockIdx.x * 256 + tid) * 4;
        float4 v = *(const float4*)(X + i);
        ushort4 h;
        h.x = f2h(v.x); h.y = f2h(v.y); h.z = f2h(v.z); h.w = f2h(v.w);
        *(ushort4*)(Xf + i) = h;
        return;
    }
    int idx = blockIdx.x - 3072;        // 0..431
    int z = idx / 144, rem = idx % 144;
    const float* W; unsigned short* T;
    if (z == 0)      { W = W0; T = T0; }
    else if (z == 1) { W = W1; T = T1; }
    else             { W = W2; T = T2; }
    int k0 = (rem / 12) << 6, n0 = (rem % 12) << 6;

    __shared__ float tile[64][65];
    const int r = tid >> 4, c4 = (tid & 15) << 2;
    #pragma unroll
    for (int i = 0; i < 4; ++i) {
        float4 v = *(const float4*)(W + (size_t)(k0 + r + i*16)*E_DIM + n0 + c4);
        tile[r + i*16][c4+0] = v.x; tile[r + i*16][c4+1] = v.y;
        tile[r + i*16][c4+2] = v.z; tile[r + i*16][c4+3] = v.w;
    }
    __syncthreads();
    #pragma unroll
    for (int i = 0; i < 4; ++i) {
        int n = r + i*16;
        ushort4 h;
        h.x = f2h(tile[c4+0][n]); h.y = f2h(tile[c4+1][n]);
        h.z = f2h(tile[c4+2][n]); h.w = f2h(tile[c4+3][n]);
        *(ushort4*)(T + (size_t)(n0 + n)*E_DIM + k0 + c4) = h;
    }
}

// ---------------------------------------------------------------------------
// Fused Q/K projection fp16 (R13-proven): 128x64 tile, grid (24,32) = 768
// blocks = 3/CU. BK=64 as two 32-k panels, all-gload16 staging.
// ---------------------------------------------------------------------------
__global__ __launch_bounds__(256) void gemm_qk_kernel(
    const unsigned short* __restrict__ A, const unsigned short* __restrict__ Bt,
    const float* __restrict__ bq, const float* __restrict__ bk,
    unsigned short* __restrict__ Qf, unsigned short* __restrict__ Kf)
{
    __shared__ unsigned short sA[2*128*32];   // [panel][m][k32]
    __shared__ unsigned short sB[2*64*32];    // [panel][n][k32]

    const int tid  = threadIdx.x;
    const int lane = tid & 63;
    const int w    = tid >> 6;
    const int qn   = lane & 15, quad = lane >> 4;
    const int wm   = w & 1, wn = w >> 1;
    const int row0 = blockIdx.y << 7;
    const int col0 = blockIdx.x << 6;   // 64-tiles: Q (<768) / K (>=768) never straddle

    const int ar = tid >> 2;            // 0..63
    const int ak = (tid & 3) << 3;      // 0,8,16,24

    const unsigned short* gA = A  + (size_t)(row0 + ar)*E_DIM + ak;
    const unsigned short* gB = Bt + (size_t)(col0 + ar)*E_DIM + ak;

    f32x4 acc[4][2];
    #pragma unroll
    for (int mt = 0; mt < 4; ++mt)
        #pragma unroll
        for (int nt = 0; nt < 2; ++nt)
            { acc[mt][nt][0]=0.f; acc[mt][nt][1]=0.f; acc[mt][nt][2]=0.f; acc[mt][nt][3]=0.f; }

    for (int k0 = 0; k0 < E_DIM; k0 += 64) {
        __syncthreads();
        gload16(gA + k0,                 sA + tid*8);
        gload16(gA + 64*E_DIM + k0,      sA + 2048 + tid*8);
        gload16(gA + k0 + 32,            sA + 4096 + tid*8);
        gload16(gA + 64*E_DIM + k0 + 32, sA + 6144 + tid*8);
        gload16(gB + k0,                 sB + tid*8);
        gload16(gB + k0 + 32,            sB + 2048 + tid*8);
        __syncthreads();

        #pragma unroll
        for (int kk = 0; kk < 2; ++kk) {
            f16x8 af[4], bf[2];
            #pragma unroll
            for (int mt = 0; mt < 4; ++mt)
                af[mt] = *(const f16x8*)&sA[kk*4096 + (wm*64 + mt*16 + qn)*32 + quad*8];
            #pragma unroll
            for (int nt = 0; nt < 2; ++nt)
                bf[nt] = *(const f16x8*)&sB[kk*2048 + (wn*32 + nt*16 + qn)*32 + quad*8];
            #pragma unroll
            for (int mt = 0; mt < 4; ++mt)
                #pragma unroll
                for (int nt = 0; nt < 2; ++nt)
                    acc[mt][nt] = MFMA16H(af[mt], bf[nt], acc[mt][nt]);
        }
    }

    #pragma unroll
    for (int nt = 0; nt < 2; ++nt) {
        int n = col0 + wn*32 + nt*16 + qn;
        bool isQ = n < E_DIM;
        float bias = isQ ? bq[n] : bk[n - E_DIM];
        unsigned short* op = isQ ? Qf : Kf;
        int nc = isQ ? n : n - E_DIM;
        #pragma unroll
        for (int mt = 0; mt < 4; ++mt)
            #pragma unroll
            for (int r = 0; r < 4; ++r) {
                int m = row0 + wm*64 + mt*16 + quad*4 + r;
                op[(size_t)m*E_DIM + nc] = f2h(acc[mt][nt][r] + bias);
            }
    }
}

// ---------------------------------------------------------------------------
// Flash attention (R13-proven, 50.3 µs plateau): 32x32x16, 4 waves, q-tile
// 128, key-split x2, dbuf sKh/sKt (one barrier/iter), strides 104/72/72,
// swapped PV, __expf.
// ---------------------------------------------------------------------------
__global__ __launch_bounds__(256) void attn_mfma_kernel(
    const unsigned short* __restrict__ Qf, const unsigned short* __restrict__ Kf,
    unsigned short* __restrict__ O0, unsigned short* __restrict__ O1,
    float2* __restrict__ ml)
{
    __shared__ unsigned short sKh[2][64][104];  // [buf][key][d]
    __shared__ unsigned short sKt[2][96][72];   // [buf][e][key]
    __shared__ unsigned short sPs[128][72];     // [q][key]

    const int tid  = threadIdx.x;
    const int w    = tid >> 6;       // wave 0..3: q rows [w*32, w*32+32)
    const int lane = tid & 63;
    const int col  = lane & 31;      // q for state/S^T-n/PV-n; e for PV-A rows
    const int half = lane >> 5;      // k-half selector
    const int b    = blockIdx.z >> 1;
    const int kh   = blockIdx.z & 1; // key half
    const int h    = blockIdx.y;
    const int q0   = blockIdx.x << 7;
    const int key0 = kh << 10;       // 0 or 1024

    // Q B-frags: B[k=d][n=q], lane reads 8 contiguous d at row q=col
    f16x8 qf[6];
    {
        const size_t ro = ((size_t)(b*S_DIM + q0 + w*32 + col))*E_DIM
                          + h*D_DIM + half*8;
        #pragma unroll
        for (int kc = 0; kc < 6; ++kc)
            qf[kc] = *(const f16x8*)(Qf + ro + kc*16);
    }

    f32x16 o[3];
    #pragma unroll
    for (int nt = 0; nt < 3; ++nt)
        #pragma unroll
        for (int r = 0; r < 16; ++r) o[nt][r] = 0.f;
    float m_i = -INFINITY, l_i = 0.f;

    // staging (threads 0-127): rows {2sp, 2sp+1}, d range [dq*24, dq*24+24)
    const bool stager = tid < 128;
    const int st = tid & 127;
    const int sp = st >> 2;          // 0..31
    const int dq = st & 3;           // 0..3

    uint4 r0[3], r1[3];
    if (stager) {
        const size_t g0 = ((size_t)(b*S_DIM + key0 + 2*sp))*E_DIM + h*D_DIM + dq*24;
        #pragma unroll
        for (int i = 0; i < 3; ++i) {
            r0[i] = *(const uint4*)(Kf + g0 + 8*i);
            r1[i] = *(const uint4*)(Kf + g0 + E_DIM + 8*i);
        }
    }

    for (int kt = 0; kt < 16; ++kt) {
        const int p = kt & 1;
        if (stager) {
            #pragma unroll
            for (int i = 0; i < 3; ++i) {
                *(uint4*)&sKh[p][2*sp  ][dq*24 + 8*i] = r0[i];
                *(uint4*)&sKh[p][2*sp+1][dq*24 + 8*i] = r1[i];
            }
            const unsigned short* p0 = (const unsigned short*)r0;
            const unsigned short* p1 = (const unsigned short*)r1;
            #pragma unroll
            for (int c = 0; c < 24; ++c) {
                unsigned int pk = (unsigned int)p0[c] | ((unsigned int)p1[c] << 16);
                *(unsigned int*)&sKt[p][dq*24 + c][2*sp] = pk;
            }
        }
        __syncthreads();   // buf[p] visible; also fences buf[p] reads of kt-2

        // prefetch next tile (overlaps with compute below)
        if (stager && kt + 1 < 16) {
            const size_t g0 = ((size_t)(b*S_DIM + key0 + (kt+1)*64 + 2*sp))*E_DIM
                              + h*D_DIM + dq*24;
            #pragma unroll
            for (int i = 0; i < 3; ++i) {
                r0[i] = *(const uint4*)(Kf + g0 + 8*i);
                r1[i] = *(const uint4*)(Kf + g0 + E_DIM + 8*i);
            }
        }

        // ---- S^T = K·Q^T (fp16), D[m=key][n=q] ----
        f32x16 s[2];
        #pragma unroll
        for (int mt = 0; mt < 2; ++mt) {
            f32x16 acc;
            #pragma unroll
            for (int r = 0; r < 16; ++r) acc[r] = 0.f;
            #pragma unroll
            for (int kc = 0; kc < 6; ++kc) {
                f16x8 ah = *(const f16x8*)&sKh[p][mt*32 + col][kc*16 + half*8];
                acc = MFMA32H(ah, qf[kc], acc);
            }
            s[mt] = acc;
        }

        // ---- online softmax, per-lane state (q = col) ----
        float mx = s[0][0];
        #pragma unroll
        for (int mt = 0; mt < 2; ++mt)
            #pragma unroll
            for (int r = 0; r < 16; ++r) mx = fmaxf(mx, s[mt][r]);
        mx = fmaxf(mx, __shfl_xor(mx, 32));

        float m_new = fmaxf(m_i, mx);
        float alpha = __expf(m_i - m_new);
        m_i = m_new;

        float psum = 0.f;
        #pragma unroll
        for (int mt = 0; mt < 2; ++mt)
            #pragma unroll
            for (int g = 0; g < 4; ++g) {
                float e0 = __expf(s[mt][4*g+0] - m_new);
                float e1 = __expf(s[mt][4*g+1] - m_new);
                float e2 = __expf(s[mt][4*g+2] - m_new);
                float e3 = __expf(s[mt][4*g+3] - m_new);
                psum += e0 + e1 + e2 + e3;
                ushort4 pk;
                pk.x = f2h(e0); pk.y = f2h(e1); pk.z = f2h(e2); pk.w = f2h(e3);
                *(ushort4*)&sPs[w*32 + col][mt*32 + 8*g + 4*half] = pk;
            }
        psum += __shfl_xor(psum, 32);
        l_i = l_i * alpha + psum;

        // rescale O: accumulator n-dim = q = col -> lane's own alpha
        #pragma unroll
        for (int nt = 0; nt < 3; ++nt)
            #pragma unroll
            for (int r = 0; r < 16; ++r) o[nt][r] *= alpha;

        // ---- PV swapped: O^T[e][q] += V^T·P^T (A = sKt rows, B = sPs rows) ----
        #pragma unroll
        for (int kc = 0; kc < 4; ++kc) {
            f16x8 pb = *(const f16x8*)&sPs[w*32 + col][kc*16 + half*8];
            #pragma unroll
            for (int nt = 0; nt < 3; ++nt) {
                f16x8 va = *(const f16x8*)&sKt[p][nt*32 + col][kc*16 + half*8];
                o[nt] = MFMA32H(va, pb, o[nt]);
            }
        }
    }

    // ---- epilogue: unnormalized Ohat (fp16), lane owns row q = col ----
    unsigned short* Ob = (kh ? O1 : O0)
        + ((size_t)(b*S_DIM + q0 + w*32 + col))*E_DIM + h*D_DIM;
    #pragma unroll
    for (int nt = 0; nt < 3; ++nt)
        #pragma unroll
        for (int rg = 0; rg < 4; ++rg) {
            ushort4 pk;
            pk.x = f2h(o[nt][4*rg+0]); pk.y = f2h(o[nt][4*rg+1]);
            pk.z = f2h(o[nt][4*rg+2]); pk.w = f2h(o[nt][4*rg+3]);
            *(ushort4*)(Ob + nt*32 + 8*rg + 4*half) = pk;
        }
    if (lane < 32) {
        int q = q0 + w*32 + lane;
        ml[((size_t)(kh*B_DIM + b)*H_DIM + h)*S_DIM + q] = make_float2(m_i, l_i);
    }
}

// ---------------------------------------------------------------------------
// Merge scales from (m,l), computed inline: s_i = exp(m_i - m) * SCALE / l
// ---------------------------------------------------------------------------
__device__ inline float2 mkscale(const float2* __restrict__ ml, int m, int h) {
    int b = m >> 11, q = m & (S_DIM - 1);
    float2 e0 = ml[((size_t)b*H_DIM + h)*S_DIM + q];
    float2 e1 = ml[((size_t)(B_DIM + b)*H_DIM + h)*S_DIM + q];
    float mm = fmaxf(e0.x, e1.x);
    float w0 = __expf(e0.x - mm), w1 = __expf(e1.x - mm);
    float inv = SCALE_F / (e0.y*w0 + e1.y*w1);
    return make_float2(w0*inv, w1*inv);
}

// ---------------------------------------------------------------------------
// Output projection + fused partial-combine, BK=64 (two 32-k panels; each
// panel lies within one head since 32 | 96, so it carries its own combine
// scale, updated only at head changes). 64x64 tile, grid (12,64) = 768
// blocks = 3/CU. 12 barrier-pairs instead of 24.
// ---------------------------------------------------------------------------
__global__ __launch_bounds__(256) void gemm_out_kernel(
    const unsigned short* __restrict__ O0, const unsigned short* __restrict__ O1,
    const float2* __restrict__ ml, const unsigned short* __restrict__ Bt,
    const float* __restrict__ bo, float* __restrict__ out)
{
    __shared__ unsigned short sA[2*64*32];   // [panel][m][k32]
    __shared__ unsigned short sB[2*64*32];

    const int tid  = threadIdx.x;
    const int lane = tid & 63;
    const int w    = tid >> 6;
    const int qn   = lane & 15, quad = lane >> 4;
    const int wm   = w & 1, wn = w >> 1;
    const int row0 = blockIdx.y << 6;
    const int col0 = blockIdx.x << 6;

    const int ar = tid >> 2;            // 0..63
    const int ak = (tid & 3) << 3;      // 0,8,16,24

    const size_t r0o = (size_t)(row0 + ar)*E_DIM;
    const unsigned short* gB = Bt + (size_t)(col0 + ar)*E_DIM + ak;

    f32x4 acc[2][2];
    #pragma unroll
    for (int mt = 0; mt < 2; ++mt)
        #pragma unroll
        for (int nt = 0; nt < 2; ++nt)
            { acc[mt][nt][0]=0.f; acc[mt][nt][1]=0.f; acc[mt][nt][2]=0.f; acc[mt][nt][3]=0.f; }

    // prefetched combine inputs for panels 0 (k0..k0+31) and 1 (k0+32..k0+63)
    f16x8 uA = *(const f16x8*)(O0 + r0o + ak);
    f16x8 vA = *(const f16x8*)(O1 + r0o + ak);
    f16x8 uB = *(const f16x8*)(O0 + r0o + 32 + ak);
    f16x8 vB = *(const f16x8*)(O1 + r0o + 32 + ak);
    int hA = 0, hB = 0;                    // heads of panels (k<96 -> both 0)
    float2 s2 = mkscale(ml, row0 + ar, 0);
    _Float16 axA = (_Float16)s2.x, ayA = (_Float16)s2.y;
    _Float16 axB = axA, ayB = ayA;

    for (int k0 = 0; k0 < E_DIM; k0 += 64) {
        __syncthreads();
        {
            f16x8 c0 = uA * axA + vA * ayA;
            f16x8 c1 = uB * axB + vB * ayB;
            *(f16x8*)&sA[       ar*32 + ak] = c0;
            *(f16x8*)&sA[2048 + ar*32 + ak] = c1;
        }
        gload16(gB + k0,      sB + tid*8);
        gload16(gB + k0 + 32, sB + 2048 + tid*8);
        __syncthreads();

        if (k0 + 64 < E_DIM) {
            int kn = k0 + 64;
            uA = *(const f16x8*)(O0 + r0o + kn + ak);
            vA = *(const f16x8*)(O1 + r0o + kn + ak);
            uB = *(const f16x8*)(O0 + r0o + kn + 32 + ak);
            vB = *(const f16x8*)(O1 + r0o + kn + 32 + ak);
            int nhA = kn / D_DIM, nhB = (kn + 32) / D_DIM;
            if (nhA != hA) {
                float2 t = mkscale(ml, row0 + ar, nhA);
                axA = (_Float16)t.x; ayA = (_Float16)t.y; hA = nhA;
            }
            if (nhB != hB) {
                float2 t = mkscale(ml, row0 + ar, nhB);
                axB = (_Float16)t.x; ayB = (_Float16)t.y; hB = nhB;
            }
        }

        #pragma unroll
        for (int kk = 0; kk < 2; ++kk) {
            f16x8 af[2], bf[2];
            #pragma unroll
            for (int mt = 0; mt < 2; ++mt)
                af[mt] = *(const f16x8*)&sA[kk*2048 + (wm*32 + mt*16 + qn)*32 + quad*8];
            #pragma unroll
            for (int nt = 0; nt < 2; ++nt)
                bf[nt] = *(const f16x8*)&sB[kk*2048 + (wn*32 + nt*16 + qn)*32 + quad*8];
            #pragma unroll
            for (int mt = 0; mt < 2; ++mt)
                #pragma unroll
                for (int nt = 0; nt < 2; ++nt)
                    acc[mt][nt] = MFMA16H(af[mt], bf[nt], acc[mt][nt]);
        }
    }

    #pragma unroll
    for (int nt = 0; nt < 2; ++nt) {
        int n = col0 + wn*32 + nt*16 + qn;
        float bias = bo[n];
        #pragma unroll
        for (int mt = 0; mt < 2; ++mt)
            #pragma unroll
            for (int r = 0; r < 4; ++r) {
                int m = row0 + wm*32 + mt*16 + quad*4 + r;
                out[(size_t)m*E_DIM + n] = acc[mt][nt][r] + bias;
            }
    }
}

// ---------------------------------------------------------------------------
extern "C" void kernel_launch(void* const* d_in, const int* in_sizes, int n_in,
                              void* d_out, int out_size, void* d_ws, size_t ws_size,
                              hipStream_t stream)
{
    const float* x  = (const float*)d_in[0];
    const float* Wq = (const float*)d_in[1];
    const float* bq = (const float*)d_in[2];
    const float* Wk = (const float*)d_in[3];
    const float* bk = (const float*)d_in[4];
    const float* Wo = (const float*)d_in[5];
    const float* bo = (const float*)d_in[6];
    float* out = (float*)d_out;

    const size_t NE = (size_t)M_DIM * E_DIM;        // 3.1M elems
    const size_t WE = (size_t)E_DIM * E_DIM;        // 590K elems
    unsigned short* xf    = (unsigned short*)d_ws;  // NE (aliased Oh0 later)
    unsigned short* WqkT  = xf + NE;                // 2*WE  [Wq^T | Wk^T] fp16
    unsigned short* WoT   = WqkT + 2*WE;            // WE
    unsigned short* Qf    = WoT + WE;               // NE
    unsigned short* Kf    = Qf + NE;                // NE
    unsigned short* Oh1   = Kf + NE;                // NE (real ws)
    float2*         mlbuf = (float2*)(Oh1 + NE);    // 2*B*H*S float2 = 512 KB
    unsigned short* Oh0   = xf;                     // alias: x dead after gemm_qk

    dim3 blk(256);
    hipLaunchKernelGGL(prep_kernel, dim3(3504), blk, 0, stream,
                       x, Wq, Wk, Wo, xf, WqkT, WqkT + WE, WoT);

    hipLaunchKernelGGL(gemm_qk_kernel, dim3(24,32), blk, 0, stream,
                       xf, WqkT, bq, bk, Qf, Kf);

    hipLaunchKernelGGL(attn_mfma_kernel, dim3(S_DIM/128, H_DIM, B_DIM*2), blk, 0,
                       stream, Qf, Kf, Oh0, Oh1, mlbuf);

    hipLaunchKernelGGL(gemm_out_kernel, dim3(12,64), blk, 0, stream,
                       Oh0, Oh1, mlbuf, WoT, bo, out);
}

// Round 17
// 157.159 us; speedup vs baseline: 1.0624x; 1.0381x over previous
//
#include <hip/hip_runtime.h>
#include <hip/hip_bf16.h>
#include <math.h>
#include <stdint.h>

#define B_DIM 2
#define S_DIM 2048
#define E_DIM 768
#define H_DIM 8
#define D_DIM 96
#define M_DIM (B_DIM*S_DIM)          // 4096
#define SCALE_F 0.10206207261596575f // 96^-0.5

typedef _Float16 f16x8 __attribute__((ext_vector_type(8)));
typedef float    f32x4  __attribute__((ext_vector_type(4)));
typedef float    f32x16 __attribute__((ext_vector_type(16)));

#define MFMA16H(a,b,c) __builtin_amdgcn_mfma_f32_16x16x32_f16(a,b,c,0,0,0)
#define MFMA32H(a,b,c) __builtin_amdgcn_mfma_f32_32x32x16_f16(a,b,c,0,0,0)

__device__ inline unsigned short f2h(float f) {
    return __builtin_bit_cast(unsigned short, (_Float16)f);
}

// CK-style async global->LDS, 16B per lane.
__device__ inline void gload16(const void* g, void* l) {
    auto gp = reinterpret_cast<const __attribute__((address_space(1))) uint32_t*>(
        reinterpret_cast<uintptr_t>(g));
    auto lp = reinterpret_cast<__attribute__((address_space(3))) uint32_t*>(
        reinterpret_cast<uintptr_t>(l));
    __builtin_amdgcn_global_load_lds(gp, lp, 16, 0, 0);
}

// ---------------------------------------------------------------------------
// Fused preprocessing, ONE launch:
//   blocks [0, 3072):   x [4096,768] fp32 -> fp16
//   blocks [3072, 3504): W{q,k,o} fp32 [k][n] -> W^T fp16 [n][k], 64x64 tiles
// ---------------------------------------------------------------------------
__global__ __launch_bounds__(256) void prep_kernel(
    const float* __restrict__ X,
    const float* __restrict__ W0, const float* __restrict__ W1,
    const float* __restrict__ W2,
    unsigned short* __restrict__ Xf,
    unsigned short* __restrict__ T0, unsigned short* __restrict__ T1,
    unsigned short* __restrict__ T2)
{
    const int tid = threadIdx.x;
    if (blockIdx.x < 3072) {
        int i = (blockIdx.x * 256 + tid) * 4;
        float4 v = *(const float4*)(X + i);
        ushort4 h;
        h.x = f2h(v.x); h.y = f2h(v.y); h.z = f2h(v.z); h.w = f2h(v.w);
        *(ushort4*)(Xf + i) = h;
        return;
    }
    int idx = blockIdx.x - 3072;        // 0..431
    int z = idx / 144, rem = idx % 144;
    const float* W; unsigned short* T;
    if (z == 0)      { W = W0; T = T0; }
    else if (z == 1) { W = W1; T = T1; }
    else             { W = W2; T = T2; }
    int k0 = (rem / 12) << 6, n0 = (rem % 12) << 6;

    __shared__ float tile[64][65];
    const int r = tid >> 4, c4 = (tid & 15) << 2;
    #pragma unroll
    for (int i = 0; i < 4; ++i) {
        float4 v = *(const float4*)(W + (size_t)(k0 + r + i*16)*E_DIM + n0 + c4);
        tile[r + i*16][c4+0] = v.x; tile[r + i*16][c4+1] = v.y;
        tile[r + i*16][c4+2] = v.z; tile[r + i*16][c4+3] = v.w;
    }
    __syncthreads();
    #pragma unroll
    for (int i = 0; i < 4; ++i) {
        int n = r + i*16;
        ushort4 h;
        h.x = f2h(tile[c4+0][n]); h.y = f2h(tile[c4+1][n]);
        h.z = f2h(tile[c4+2][n]); h.w = f2h(tile[c4+3][n]);
        *(ushort4*)(T + (size_t)(n0 + n)*E_DIM + k0 + c4) = h;
    }
}

// ---------------------------------------------------------------------------
// Fused Q/K projection fp16: 128x64 tile, 768 blocks (1-D), BK=64 as two
// 32-k panels. XCD-AWARE SWIZZLE: blocks with the same id%8 (same XCD under
// round-robin dispatch) share 4 row-panels and sweep all 24 col-tiles, so
// the per-XCD working set (4 A-panels 786 KB + full B 2.25 MB) stays L2-hot.
// ---------------------------------------------------------------------------
__global__ __launch_bounds__(256) void gemm_qk_kernel(
    const unsigned short* __restrict__ A, const unsigned short* __restrict__ Bt,
    const float* __restrict__ bq, const float* __restrict__ bk,
    unsigned short* __restrict__ Qf, unsigned short* __restrict__ Kf)
{
    __shared__ unsigned short sA[2*128*32];   // [panel][m][k32]
    __shared__ unsigned short sB[2*64*32];    // [panel][n][k32]

    const int tid  = threadIdx.x;
    const int lane = tid & 63;
    const int w    = tid >> 6;
    const int qn   = lane & 15, quad = lane >> 4;
    const int wm   = w & 1, wn = w >> 1;

    // XCD swizzle: g = id%8 (XCD), s = id/8; rows g*4+(s%4), col s/4
    const int flat = blockIdx.x;            // 0..767
    const int g = flat & 7, s = flat >> 3;  // s: 0..95
    const int row0 = ((g << 2) + (s & 3)) << 7;   // 32 row-panels of 128
    const int col0 = (s >> 2) << 6;               // 24 col-tiles of 64

    const int ar = tid >> 2;            // 0..63
    const int ak = (tid & 3) << 3;      // 0,8,16,24

    const unsigned short* gA = A  + (size_t)(row0 + ar)*E_DIM + ak;
    const unsigned short* gB = Bt + (size_t)(col0 + ar)*E_DIM + ak;

    f32x4 acc[4][2];
    #pragma unroll
    for (int mt = 0; mt < 4; ++mt)
        #pragma unroll
        for (int nt = 0; nt < 2; ++nt)
            { acc[mt][nt][0]=0.f; acc[mt][nt][1]=0.f; acc[mt][nt][2]=0.f; acc[mt][nt][3]=0.f; }

    for (int k0 = 0; k0 < E_DIM; k0 += 64) {
        __syncthreads();
        gload16(gA + k0,                 sA + tid*8);
        gload16(gA + 64*E_DIM + k0,      sA + 2048 + tid*8);
        gload16(gA + k0 + 32,            sA + 4096 + tid*8);
        gload16(gA + 64*E_DIM + k0 + 32, sA + 6144 + tid*8);
        gload16(gB + k0,                 sB + tid*8);
        gload16(gB + k0 + 32,            sB + 2048 + tid*8);
        __syncthreads();

        #pragma unroll
        for (int kk = 0; kk < 2; ++kk) {
            f16x8 af[4], bf[2];
            #pragma unroll
            for (int mt = 0; mt < 4; ++mt)
                af[mt] = *(const f16x8*)&sA[kk*4096 + (wm*64 + mt*16 + qn)*32 + quad*8];
            #pragma unroll
            for (int nt = 0; nt < 2; ++nt)
                bf[nt] = *(const f16x8*)&sB[kk*2048 + (wn*32 + nt*16 + qn)*32 + quad*8];
            #pragma unroll
            for (int mt = 0; mt < 4; ++mt)
                #pragma unroll
                for (int nt = 0; nt < 2; ++nt)
                    acc[mt][nt] = MFMA16H(af[mt], bf[nt], acc[mt][nt]);
        }
    }

    #pragma unroll
    for (int nt = 0; nt < 2; ++nt) {
        int n = col0 + wn*32 + nt*16 + qn;
        bool isQ = n < E_DIM;
        float bias = isQ ? bq[n] : bk[n - E_DIM];
        unsigned short* op = isQ ? Qf : Kf;
        int nc = isQ ? n : n - E_DIM;
        #pragma unroll
        for (int mt = 0; mt < 4; ++mt)
            #pragma unroll
            for (int r = 0; r < 4; ++r) {
                int m = row0 + wm*64 + mt*16 + quad*4 + r;
                op[(size_t)m*E_DIM + nc] = f2h(acc[mt][nt][r] + bias);
            }
    }
}

// ---------------------------------------------------------------------------
// Flash attention (R13/R15-proven, 49.6 µs plateau): 32x32x16, 4 waves,
// q-tile 128, key-split x2, dbuf sKh/sKt (one barrier/iter), strides
// 104/72/72, swapped PV, __expf.
// ---------------------------------------------------------------------------
__global__ __launch_bounds__(256) void attn_mfma_kernel(
    const unsigned short* __restrict__ Qf, const unsigned short* __restrict__ Kf,
    unsigned short* __restrict__ O0, unsigned short* __restrict__ O1,
    float2* __restrict__ ml)
{
    __shared__ unsigned short sKh[2][64][104];  // [buf][key][d]
    __shared__ unsigned short sKt[2][96][72];   // [buf][e][key]
    __shared__ unsigned short sPs[128][72];     // [q][key]

    const int tid  = threadIdx.x;
    const int w    = tid >> 6;       // wave 0..3: q rows [w*32, w*32+32)
    const int lane = tid & 63;
    const int col  = lane & 31;      // q for state/S^T-n/PV-n; e for PV-A rows
    const int half = lane >> 5;      // k-half selector
    const int b    = blockIdx.z >> 1;
    const int kh   = blockIdx.z & 1; // key half
    const int h    = blockIdx.y;
    const int q0   = blockIdx.x << 7;
    const int key0 = kh << 10;       // 0 or 1024

    // Q B-frags: B[k=d][n=q], lane reads 8 contiguous d at row q=col
    f16x8 qf[6];
    {
        const size_t ro = ((size_t)(b*S_DIM + q0 + w*32 + col))*E_DIM
                          + h*D_DIM + half*8;
        #pragma unroll
        for (int kc = 0; kc < 6; ++kc)
            qf[kc] = *(const f16x8*)(Qf + ro + kc*16);
    }

    f32x16 o[3];
    #pragma unroll
    for (int nt = 0; nt < 3; ++nt)
        #pragma unroll
        for (int r = 0; r < 16; ++r) o[nt][r] = 0.f;
    float m_i = -INFINITY, l_i = 0.f;

    // staging (threads 0-127): rows {2sp, 2sp+1}, d range [dq*24, dq*24+24)
    const bool stager = tid < 128;
    const int st = tid & 127;
    const int sp = st >> 2;          // 0..31
    const int dq = st & 3;           // 0..3

    uint4 r0[3], r1[3];
    if (stager) {
        const size_t g0 = ((size_t)(b*S_DIM + key0 + 2*sp))*E_DIM + h*D_DIM + dq*24;
        #pragma unroll
        for (int i = 0; i < 3; ++i) {
            r0[i] = *(const uint4*)(Kf + g0 + 8*i);
            r1[i] = *(const uint4*)(Kf + g0 + E_DIM + 8*i);
        }
    }

    for (int kt = 0; kt < 16; ++kt) {
        const int p = kt & 1;
        if (stager) {
            #pragma unroll
            for (int i = 0; i < 3; ++i) {
                *(uint4*)&sKh[p][2*sp  ][dq*24 + 8*i] = r0[i];
                *(uint4*)&sKh[p][2*sp+1][dq*24 + 8*i] = r1[i];
            }
            const unsigned short* p0 = (const unsigned short*)r0;
            const unsigned short* p1 = (const unsigned short*)r1;
            #pragma unroll
            for (int c = 0; c < 24; ++c) {
                unsigned int pk = (unsigned int)p0[c] | ((unsigned int)p1[c] << 16);
                *(unsigned int*)&sKt[p][dq*24 + c][2*sp] = pk;
            }
        }
        __syncthreads();   // buf[p] visible; also fences buf[p] reads of kt-2

        // prefetch next tile (overlaps with compute below)
        if (stager && kt + 1 < 16) {
            const size_t g0 = ((size_t)(b*S_DIM + key0 + (kt+1)*64 + 2*sp))*E_DIM
                              + h*D_DIM + dq*24;
            #pragma unroll
            for (int i = 0; i < 3; ++i) {
                r0[i] = *(const uint4*)(Kf + g0 + 8*i);
                r1[i] = *(const uint4*)(Kf + g0 + E_DIM + 8*i);
            }
        }

        // ---- S^T = K·Q^T (fp16), D[m=key][n=q] ----
        f32x16 s[2];
        #pragma unroll
        for (int mt = 0; mt < 2; ++mt) {
            f32x16 acc;
            #pragma unroll
            for (int r = 0; r < 16; ++r) acc[r] = 0.f;
            #pragma unroll
            for (int kc = 0; kc < 6; ++kc) {
                f16x8 ah = *(const f16x8*)&sKh[p][mt*32 + col][kc*16 + half*8];
                acc = MFMA32H(ah, qf[kc], acc);
            }
            s[mt] = acc;
        }

        // ---- online softmax, per-lane state (q = col) ----
        float mx = s[0][0];
        #pragma unroll
        for (int mt = 0; mt < 2; ++mt)
            #pragma unroll
            for (int r = 0; r < 16; ++r) mx = fmaxf(mx, s[mt][r]);
        mx = fmaxf(mx, __shfl_xor(mx, 32));

        float m_new = fmaxf(m_i, mx);
        float alpha = __expf(m_i - m_new);
        m_i = m_new;

        float psum = 0.f;
        #pragma unroll
        for (int mt = 0; mt < 2; ++mt)
            #pragma unroll
            for (int g = 0; g < 4; ++g) {
                float e0 = __expf(s[mt][4*g+0] - m_new);
                float e1 = __expf(s[mt][4*g+1] - m_new);
                float e2 = __expf(s[mt][4*g+2] - m_new);
                float e3 = __expf(s[mt][4*g+3] - m_new);
                psum += e0 + e1 + e2 + e3;
                ushort4 pk;
                pk.x = f2h(e0); pk.y = f2h(e1); pk.z = f2h(e2); pk.w = f2h(e3);
                *(ushort4*)&sPs[w*32 + col][mt*32 + 8*g + 4*half] = pk;
            }
        psum += __shfl_xor(psum, 32);
        l_i = l_i * alpha + psum;

        // rescale O: accumulator n-dim = q = col -> lane's own alpha
        #pragma unroll
        for (int nt = 0; nt < 3; ++nt)
            #pragma unroll
            for (int r = 0; r < 16; ++r) o[nt][r] *= alpha;

        // ---- PV swapped: O^T[e][q] += V^T·P^T (A = sKt rows, B = sPs rows) ----
        #pragma unroll
        for (int kc = 0; kc < 4; ++kc) {
            f16x8 pb = *(const f16x8*)&sPs[w*32 + col][kc*16 + half*8];
            #pragma unroll
            for (int nt = 0; nt < 3; ++nt) {
                f16x8 va = *(const f16x8*)&sKt[p][nt*32 + col][kc*16 + half*8];
                o[nt] = MFMA32H(va, pb, o[nt]);
            }
        }
    }

    // ---- epilogue: unnormalized Ohat (fp16), lane owns row q = col ----
    unsigned short* Ob = (kh ? O1 : O0)
        + ((size_t)(b*S_DIM + q0 + w*32 + col))*E_DIM + h*D_DIM;
    #pragma unroll
    for (int nt = 0; nt < 3; ++nt)
        #pragma unroll
        for (int rg = 0; rg < 4; ++rg) {
            ushort4 pk;
            pk.x = f2h(o[nt][4*rg+0]); pk.y = f2h(o[nt][4*rg+1]);
            pk.z = f2h(o[nt][4*rg+2]); pk.w = f2h(o[nt][4*rg+3]);
            *(ushort4*)(Ob + nt*32 + 8*rg + 4*half) = pk;
        }
    if (lane < 32) {
        int q = q0 + w*32 + lane;
        ml[((size_t)(kh*B_DIM + b)*H_DIM + h)*S_DIM + q] = make_float2(m_i, l_i);
    }
}

// ---------------------------------------------------------------------------
// Merge scales from (m,l), computed inline: s_i = exp(m_i - m) * SCALE / l
// ---------------------------------------------------------------------------
__device__ inline float2 mkscale(const float2* __restrict__ ml, int m, int h) {
    int b = m >> 11, q = m & (S_DIM - 1);
    float2 e0 = ml[((size_t)b*H_DIM + h)*S_DIM + q];
    float2 e1 = ml[((size_t)(B_DIM + b)*H_DIM + h)*S_DIM + q];
    float mm = fmaxf(e0.x, e1.x);
    float w0 = __expf(e0.x - mm), w1 = __expf(e1.x - mm);
    float inv = SCALE_F / (e0.y*w0 + e1.y*w1);
    return make_float2(w0*inv, w1*inv);
}

// ---------------------------------------------------------------------------
// Output projection + fused partial-combine, BK=64 (R15-proven) with XCD
// swizzle: id%8 groups share 8 row-panels, sweep 12 col-tiles; per-XCD
// working set (O0/O1 slices 1.6 MB + WoT 1.1 MB) stays L2-hot.
// ---------------------------------------------------------------------------
__global__ __launch_bounds__(256) void gemm_out_kernel(
    const unsigned short* __restrict__ O0, const unsigned short* __restrict__ O1,
    const float2* __restrict__ ml, const unsigned short* __restrict__ Bt,
    const float* __restrict__ bo, float* __restrict__ out)
{
    __shared__ unsigned short sA[2*64*32];   // [panel][m][k32]
    __shared__ unsigned short sB[2*64*32];

    const int tid  = threadIdx.x;
    const int lane = tid & 63;
    const int w    = tid >> 6;
    const int qn   = lane & 15, quad = lane >> 4;
    const int wm   = w & 1, wn = w >> 1;

    // XCD swizzle: g = id%8, s = id/8; rows g*8+(s%8), col s/8
    const int flat = blockIdx.x;            // 0..767
    const int g = flat & 7, s = flat >> 3;  // s: 0..95
    const int row0 = ((g << 3) + (s & 7)) << 6;   // 64 row-panels of 64
    const int col0 = (s >> 3) << 6;               // 12 col-tiles of 64

    const int ar = tid >> 2;            // 0..63
    const int ak = (tid & 3) << 3;      // 0,8,16,24

    const size_t r0o = (size_t)(row0 + ar)*E_DIM;
    const unsigned short* gB = Bt + (size_t)(col0 + ar)*E_DIM + ak;

    f32x4 acc[2][2];
    #pragma unroll
    for (int mt = 0; mt < 2; ++mt)
        #pragma unroll
        for (int nt = 0; nt < 2; ++nt)
            { acc[mt][nt][0]=0.f; acc[mt][nt][1]=0.f; acc[mt][nt][2]=0.f; acc[mt][nt][3]=0.f; }

    // prefetched combine inputs for panels 0 (k0..k0+31) and 1 (k0+32..k0+63)
    f16x8 uA = *(const f16x8*)(O0 + r0o + ak);
    f16x8 vA = *(const f16x8*)(O1 + r0o + ak);
    f16x8 uB = *(const f16x8*)(O0 + r0o + 32 + ak);
    f16x8 vB = *(const f16x8*)(O1 + r0o + 32 + ak);
    int hA = 0, hB = 0;                    // heads of panels (k<96 -> both 0)
    float2 s2 = mkscale(ml, row0 + ar, 0);
    _Float16 axA = (_Float16)s2.x, ayA = (_Float16)s2.y;
    _Float16 axB = axA, ayB = ayA;

    for (int k0 = 0; k0 < E_DIM; k0 += 64) {
        __syncthreads();
        {
            f16x8 c0 = uA * axA + vA * ayA;
            f16x8 c1 = uB * axB + vB * ayB;
            *(f16x8*)&sA[       ar*32 + ak] = c0;
            *(f16x8*)&sA[2048 + ar*32 + ak] = c1;
        }
        gload16(gB + k0,      sB + tid*8);
        gload16(gB + k0 + 32, sB + 2048 + tid*8);
        __syncthreads();

        if (k0 + 64 < E_DIM) {
            int kn = k0 + 64;
            uA = *(const f16x8*)(O0 + r0o + kn + ak);
            vA = *(const f16x8*)(O1 + r0o + kn + ak);
            uB = *(const f16x8*)(O0 + r0o + kn + 32 + ak);
            vB = *(const f16x8*)(O1 + r0o + kn + 32 + ak);
            int nhA = kn / D_DIM, nhB = (kn + 32) / D_DIM;
            if (nhA != hA) {
                float2 t = mkscale(ml, row0 + ar, nhA);
                axA = (_Float16)t.x; ayA = (_Float16)t.y; hA = nhA;
            }
            if (nhB != hB) {
                float2 t = mkscale(ml, row0 + ar, nhB);
                axB = (_Float16)t.x; ayB = (_Float16)t.y; hB = nhB;
            }
        }

        #pragma unroll
        for (int kk = 0; kk < 2; ++kk) {
            f16x8 af[2], bf[2];
            #pragma unroll
            for (int mt = 0; mt < 2; ++mt)
                af[mt] = *(const f16x8*)&sA[kk*2048 + (wm*32 + mt*16 + qn)*32 + quad*8];
            #pragma unroll
            for (int nt = 0; nt < 2; ++nt)
                bf[nt] = *(const f16x8*)&sB[kk*2048 + (wn*32 + nt*16 + qn)*32 + quad*8];
            #pragma unroll
            for (int mt = 0; mt < 2; ++mt)
                #pragma unroll
                for (int nt = 0; nt < 2; ++nt)
                    acc[mt][nt] = MFMA16H(af[mt], bf[nt], acc[mt][nt]);
        }
    }

    #pragma unroll
    for (int nt = 0; nt < 2; ++nt) {
        int n = col0 + wn*32 + nt*16 + qn;
        float bias = bo[n];
        #pragma unroll
        for (int mt = 0; mt < 2; ++mt)
            #pragma unroll
            for (int r = 0; r < 4; ++r) {
                int m = row0 + wm*32 + mt*16 + quad*4 + r;
                out[(size_t)m*E_DIM + n] = acc[mt][nt][r] + bias;
            }
    }
}

// ---------------------------------------------------------------------------
extern "C" void kernel_launch(void* const* d_in, const int* in_sizes, int n_in,
                              void* d_out, int out_size, void* d_ws, size_t ws_size,
                              hipStream_t stream)
{
    const float* x  = (const float*)d_in[0];
    const float* Wq = (const float*)d_in[1];
    const float* bq = (const float*)d_in[2];
    const float* Wk = (const float*)d_in[3];
    const float* bk = (const float*)d_in[4];
    const float* Wo = (const float*)d_in[5];
    const float* bo = (const float*)d_in[6];
    float* out = (float*)d_out;

    const size_t NE = (size_t)M_DIM * E_DIM;        // 3.1M elems
    const size_t WE = (size_t)E_DIM * E_DIM;        // 590K elems
    unsigned short* xf    = (unsigned short*)d_ws;  // NE (aliased Oh0 later)
    unsigned short* WqkT  = xf + NE;                // 2*WE  [Wq^T | Wk^T] fp16
    unsigned short* WoT   = WqkT + 2*WE;            // WE
    unsigned short* Qf    = WoT + WE;               // NE
    unsigned short* Kf    = Qf + NE;                // NE
    unsigned short* Oh1   = Kf + NE;                // NE (real ws)
    float2*         mlbuf = (float2*)(Oh1 + NE);    // 2*B*H*S float2 = 512 KB
    unsigned short* Oh0   = xf;                     // alias: x dead after gemm_qk

    dim3 blk(256);
    hipLaunchKernelGGL(prep_kernel, dim3(3504), blk, 0, stream,
                       x, Wq, Wk, Wo, xf, WqkT, WqkT + WE, WoT);

    hipLaunchKernelGGL(gemm_qk_kernel, dim3(768), blk, 0, stream,
                       xf, WqkT, bq, bk, Qf, Kf);

    hipLaunchKernelGGL(attn_mfma_kernel, dim3(S_DIM/128, H_DIM, B_DIM*2), blk, 0,
                       stream, Qf, Kf, Oh0, Oh1, mlbuf);

    hipLaunchKernelGGL(gemm_out_kernel, dim3(768), blk, 0, stream,
                       Oh0, Oh1, mlbuf, WoT, bo, out);
}